// Round 5
// baseline (145.613 us; speedup 1.0000x reference)
//
#include <hip/hip_runtime.h>
#include <hip/hip_bf16.h>

// d[e] = || R[idx_i[e]] - R[idx_j[e]] ||
//
// R1-R4 model: bound by per-CU miss tracking: 12.8M random-line misses at
// ~3.2 cy/miss/CU (= ~64 MSHRs / ~208cy L2 latency), invariant to
// instruction shape (R1=R2), nt (R3), sc0 (R4).
// R5 experiment: split gathers across TWO hardware paths -
//   A-side: register-return gathers (sc0),
//   B-side: LDS-DMA gathers (global_load_lds, per-lane source address,
//           dest = wave-uniform base + lane*16).
// If the LDS-DMA path has an independent outstanding-miss budget, the two
// streams overlap -> ~2x. If shared, flat -> MSHR roofline confirmed.

typedef int   v4i __attribute__((ext_vector_type(4)));
typedef float v4f __attribute__((ext_vector_type(4)));

__global__ __launch_bounds__(256) void pad_R_kernel(
    const float* __restrict__ R, float* __restrict__ R4, int n_atoms)
{
    const int i = blockIdx.x * blockDim.x + threadIdx.x;
    if (i < n_atoms) {
        const float x = R[3 * i + 0];
        const float y = R[3 * i + 1];
        const float z = R[3 * i + 2];
        v4f v = {x, y, z, 0.0f};
        *(v4f*)(R4 + 4 * (size_t)i) = v;
    }
}

// Register-path gather, L1 no-allocate (sc0).
__device__ __forceinline__ v4f gather_sc0(const float* base, int idx)
{
    v4f r;
    const int voff = idx << 4;
    asm volatile("global_load_dwordx4 %0, %1, %2 sc0"
                 : "=v"(r)
                 : "v"(voff), "s"(base)
                 : "memory");
    return r;
}

// LDS-DMA gather: 16B from per-lane global address into
// (wave-uniform lds base) + lane*16.
__device__ __forceinline__ void gather_to_lds(const float* gaddr, float* lbase)
{
    __builtin_amdgcn_global_load_lds(
        (const __attribute__((address_space(1))) void*)gaddr,
        (__attribute__((address_space(3))) void*)lbase,
        16, 0, 0);
}

__device__ __forceinline__ float dist3(v4f a, v4f b)
{
    const v4f d = a - b;
    return sqrtf(d.x * d.x + d.y * d.y + d.z * d.z);
}

// Each block: 2048 edges (512 quads). Thread t handles quads
// blockIdx*512 + t and +256 (coalesced int4 idx loads / float4 stores).
__global__ __launch_bounds__(256) void pairwise_dist_kernel(
    const float* __restrict__ R4,
    const int* __restrict__ idx_i,
    const int* __restrict__ idx_j,
    float* __restrict__ out)
{
    __shared__ float lds[4 * 8 * 256];   // 4 waves x 8 regions x 1KB = 32 KB
    const int tid  = threadIdx.x;
    const int lane = tid & 63;
    const int wave = tid >> 6;
    float* wbase = &lds[wave * 8 * 256];

    const int q0 = blockIdx.x * 512 + tid;
    const int q1 = q0 + 256;

    const v4i a0 = ((const v4i*)idx_i)[q0];
    const v4i a1 = ((const v4i*)idx_i)[q1];
    const v4i b0 = ((const v4i*)idx_j)[q0];
    const v4i b1 = ((const v4i*)idx_j)[q1];

    // B-side: 8 LDS-DMA gathers (per-lane source addresses).
    gather_to_lds(R4 + 4 * (size_t)b0.x, wbase + 0 * 256);
    gather_to_lds(R4 + 4 * (size_t)b0.y, wbase + 1 * 256);
    gather_to_lds(R4 + 4 * (size_t)b0.z, wbase + 2 * 256);
    gather_to_lds(R4 + 4 * (size_t)b0.w, wbase + 3 * 256);
    gather_to_lds(R4 + 4 * (size_t)b1.x, wbase + 4 * 256);
    gather_to_lds(R4 + 4 * (size_t)b1.y, wbase + 5 * 256);
    gather_to_lds(R4 + 4 * (size_t)b1.z, wbase + 6 * 256);
    gather_to_lds(R4 + 4 * (size_t)b1.w, wbase + 7 * 256);

    // A-side: 8 register-path gathers, in flight concurrently.
    v4f pa0 = gather_sc0(R4, a0.x);
    v4f pa1 = gather_sc0(R4, a0.y);
    v4f pa2 = gather_sc0(R4, a0.z);
    v4f pa3 = gather_sc0(R4, a0.w);
    v4f pa4 = gather_sc0(R4, a1.x);
    v4f pa5 = gather_sc0(R4, a1.y);
    v4f pa6 = gather_sc0(R4, a1.z);
    v4f pa7 = gather_sc0(R4, a1.w);

    // Drain all vmem (compiler does not track LDS-DMA -> ds_read deps).
    asm volatile("s_waitcnt vmcnt(0)" ::: "memory");

    const v4f pb0 = *(const v4f*)(wbase + 0 * 256 + lane * 4);
    const v4f pb1 = *(const v4f*)(wbase + 1 * 256 + lane * 4);
    const v4f pb2 = *(const v4f*)(wbase + 2 * 256 + lane * 4);
    const v4f pb3 = *(const v4f*)(wbase + 3 * 256 + lane * 4);
    const v4f pb4 = *(const v4f*)(wbase + 4 * 256 + lane * 4);
    const v4f pb5 = *(const v4f*)(wbase + 5 * 256 + lane * 4);
    const v4f pb6 = *(const v4f*)(wbase + 6 * 256 + lane * 4);
    const v4f pb7 = *(const v4f*)(wbase + 7 * 256 + lane * 4);

    v4f o0, o1;
    o0.x = dist3(pa0, pb0);
    o0.y = dist3(pa1, pb1);
    o0.z = dist3(pa2, pb2);
    o0.w = dist3(pa3, pb3);
    o1.x = dist3(pa4, pb4);
    o1.y = dist3(pa5, pb5);
    o1.z = dist3(pa6, pb6);
    o1.w = dist3(pa7, pb7);

    ((v4f*)out)[q0] = o0;
    ((v4f*)out)[q1] = o1;
}

__global__ __launch_bounds__(64) void pairwise_dist_tail_kernel(
    const float* __restrict__ R4,
    const int* __restrict__ idx_i,
    const int* __restrict__ idx_j,
    float* __restrict__ out,
    int start, int n_edges)
{
    const int e = start + blockIdx.x * blockDim.x + threadIdx.x;
    if (e < n_edges) {
        const v4f pa = *(const v4f*)(R4 + 4 * (size_t)idx_i[e]);
        const v4f pb = *(const v4f*)(R4 + 4 * (size_t)idx_j[e]);
        out[e] = dist3(pa, pb);
    }
}

extern "C" void kernel_launch(void* const* d_in, const int* in_sizes, int n_in,
                              void* d_out, int out_size, void* d_ws, size_t ws_size,
                              hipStream_t stream)
{
    const float* R     = (const float*)d_in[0];
    const int*   idx_i = (const int*)d_in[1];
    const int*   idx_j = (const int*)d_in[2];
    float*       out   = (float*)d_out;

    const int n_atoms = in_sizes[0] / 3;        // 100,000
    const int n_edges = in_sizes[1];            // 6,400,000
    float*    R4      = (float*)d_ws;           // n_atoms * 4 floats = 1.6 MB

    {
        const int block = 256;
        const int grid  = (n_atoms + block - 1) / block;
        pad_R_kernel<<<grid, block, 0, stream>>>(R, R4, n_atoms);
    }

    const int n_full_blocks = n_edges / 2048;   // 3125 for 6.4M (exact)
    if (n_full_blocks > 0) {
        pairwise_dist_kernel<<<n_full_blocks, 256, 0, stream>>>(
            R4, idx_i, idx_j, out);
    }

    const int done = n_full_blocks * 2048;
    if (done < n_edges) {
        const int tail = n_edges - done;
        pairwise_dist_tail_kernel<<<(tail + 63) / 64, 64, 0, stream>>>(
            R4, idx_i, idx_j, out, done, n_edges);
    }
}